// Round 9
// baseline (110.544 us; speedup 1.0000x reference)
//
#include <hip/hip_runtime.h>

#define BB 8
#define TT 24
#define NN 4096   // C*C
#define HH 32
#define JT 32     // j-tile width
#define NBLK (NN/JT)   // 128 blocks per batch
#define UPB (TT*HH)    // 768
#define CTRS 16   // counter stride (words)

// ---------------- K1: norm only (192 blocks); zero u + ctr ----------------
__global__ __launch_bounds__(256) void k_norm(const float* __restrict__ Flow,
                                              float* __restrict__ rn,
                                              float* __restrict__ s,
                                              float* __restrict__ uz) {
    const int blk = blockIdx.x;
    const int tid = threadIdx.x;
    const float4* x = (const float4*)(Flow + (size_t)blk * NN);
    float sq = 0.f, sm = 0.f;
#pragma unroll
    for (int i = 0; i < 4; ++i) {
        float4 v = x[tid + i * 256];
        sq += v.x * v.x + v.y * v.y + v.z * v.z + v.w * v.w;
        sm += v.x + v.y + v.z + v.w;
    }
#pragma unroll
    for (int off = 32; off > 0; off >>= 1) {
        sq += __shfl_down(sq, off);
        sm += __shfl_down(sm, off);
    }
    __shared__ float rss[4], rsm[4];
    int wave = tid >> 6, lane = tid & 63;
    if (lane == 0) { rss[wave] = sq; rsm[wave] = sm; }
    __syncthreads();
    if (tid == 0) {
        float tss = rss[0] + rss[1] + rss[2] + rss[3];
        float tsm = rsm[0] + rsm[1] + rsm[2] + rsm[3];
        float r = 1.0f / fmaxf(sqrtf(tss), 1e-12f);
        rn[blk] = r;
        s[blk] = tsm * r;
    }
    // zero u (18432) + counters (384)
    int gid = blk * 256 + tid;
    if (gid < 3 * BB * TT * HH + 3 * BB * CTRS) uz[gid] = 0.f;
}

// ---------------- K2: persistent 3-layer kernel, per-batch relaxed barriers ----------------
// Validated R7: relaxed memory-side counter barrier + atomic-only u accesses.
__global__ __launch_bounds__(256, 4) void k_mega(const float* __restrict__ Flow,
                                                 const float* __restrict__ Edge,
                                                 const float* __restrict__ W0,
                                                 const float* __restrict__ W1,
                                                 const float* __restrict__ W2,
                                                 const float* __restrict__ b0,
                                                 const float* __restrict__ b1,
                                                 const float* __restrict__ b2,
                                                 const float* __restrict__ rn,
                                                 const float* __restrict__ s,
                                                 float* __restrict__ u,
                                                 unsigned* __restrict__ ctr,
                                                 float* __restrict__ out) {
    const int blk = blockIdx.x;
    const int b = blk >> 7;                 // batch-contiguous block IDs
    const int j0 = (blk & (NBLK - 1)) * JT;
    const int tid = threadIdx.x;

    __shared__ float xns[TT][JT];           // 3 KB
    __shared__ float zs[JT][HH + 1];        // 4.125 KB
    __shared__ float xs[JT][HH + 1];        // 4.125 KB
    __shared__ float W0s[32][32], W1s[32][32], W2s[32][32];  // 12 KB
    __shared__ float us[TT][HH];            // 3 KB
    __shared__ float sS[TT], rnS[TT];
    __shared__ float b0s[32], b1s[32], b2s[32];

    if (tid < TT) { sS[tid] = s[b * TT + tid]; rnS[tid] = rn[b * TT + tid]; }
    if (tid < 32) { b0s[tid] = b0[tid]; b1s[tid] = b1[tid]; b2s[tid] = b2[tid]; }
    __syncthreads();

    for (int i = tid; i < 1024; i += 256) {
        W0s[i >> 5][i & 31] = W0[i];
        W1s[i >> 5][i & 31] = W1[i];
        W2s[i >> 5][i & 31] = W2[i];
    }
    // Edge tile (32x32): one float4 per thread
    {
        float4 v = ((const float4*)(Edge + ((size_t)b * NN + j0) * HH))[tid];
        int r0 = tid >> 3, c0 = (tid & 7) * 4;
        xs[r0][c0] = v.x; xs[r0][c0 + 1] = v.y; xs[r0][c0 + 2] = v.z; xs[r0][c0 + 3] = v.w;
    }
    // Flow tile scaled -> xn tile (24x32): 192 float4
    if (tid < TT * (JT / 4)) {
        int t = tid >> 3, c0 = (tid & 7) * 4;
        float4 v = ((const float4*)(Flow + (size_t)b * TT * NN + (size_t)t * NN + j0))[tid & 7];
        float rt = rnS[t];
        xns[t][c0] = v.x * rt; xns[t][c0 + 1] = v.y * rt;
        xns[t][c0 + 2] = v.z * rt; xns[t][c0 + 3] = v.w * rt;
    }
    __syncthreads();

    const int r = tid >> 3;            // 0..31
    const int h0 = (tid & 7) * 4;      // 0,4,...,28
    float deg = 1.0f;
#pragma unroll
    for (int t = 0; t < TT; ++t) deg += xns[t][r] * sS[t];
    const float di = (deg > 0.f) ? rsqrtf(deg) : 0.f;

    // z0 = di .* (Edge @ W0)
#pragma unroll
    for (int hh = 0; hh < 4; ++hh) {
        float acc = 0.f;
#pragma unroll
        for (int e = 0; e < 32; ++e) acc += xs[r][e] * W0s[e][h0 + hh];
        zs[r][h0 + hh] = di * acc;
    }
    __syncthreads();

    float* u0 = u + b * UPB;
    float* u1 = u0 + BB * UPB;
    float* u2 = u1 + BB * UPB;

#define U_PART(dst)                                                        \
    {                                                                      \
        _Pragma("unroll")                                                  \
        for (int k = 0; k < 3; ++k) {                                      \
            int p = tid + k * 256;                                         \
            int t = p >> 5, h = p & 31;                                    \
            float acc = 0.f;                                               \
            _Pragma("unroll 8")                                            \
            for (int rr = 0; rr < JT; ++rr) acc += xns[t][rr] * zs[rr][h]; \
            atomicAdd(&(dst)[t * HH + h], acc);                            \
        }                                                                  \
    }

#define BAR(phase)                                                                  \
    {                                                                               \
        __syncthreads(); /* compiler drains vmcnt before s_barrier */               \
        if (tid == 0) {                                                             \
            unsigned* c = ctr + ((phase) * BB + b) * CTRS;                          \
            __hip_atomic_fetch_add(c, 1u, __ATOMIC_RELAXED, __HIP_MEMORY_SCOPE_AGENT); \
            while (__hip_atomic_load(c, __ATOMIC_RELAXED, __HIP_MEMORY_SCOPE_AGENT) < (unsigned)NBLK) \
                __builtin_amdgcn_s_sleep(4);                                        \
        }                                                                           \
        __syncthreads();                                                            \
    }

#define LOAD_US(src)                                                                \
    {                                                                               \
        _Pragma("unroll")                                                           \
        for (int k = 0; k < 3; ++k) {                                               \
            int p = tid + k * 256;                                                  \
            us[p >> 5][p & 31] = __hip_atomic_load(&(src)[p], __ATOMIC_RELAXED,     \
                                                   __HIP_MEMORY_SCOPE_AGENT);       \
        }                                                                           \
        __syncthreads();                                                            \
    }

    // ---- layer 0 reduction ----
    U_PART(u0);
    BAR(0);
    LOAD_US(u0);

    // ---- layer 1 ----
#pragma unroll
    for (int hh = 0; hh < 4; ++hh) {
        int h = h0 + hh;
        float acc = 0.f;
#pragma unroll
        for (int t = 0; t < TT; ++t) acc += xns[t][r] * us[t][h];
        xs[r][h] = fmaxf(di * (acc + zs[r][h]) + b0s[h], 0.f);
    }
    // threads r*8..r*8+7 (same wave64) wrote xs[r][0..31]: program-order LDS
    // visibility within a wave (validated R1..R7)
#pragma unroll
    for (int hh = 0; hh < 4; ++hh) {
        float acc = 0.f;
#pragma unroll
        for (int e = 0; e < 32; ++e) acc += xs[r][e] * W1s[e][h0 + hh];
        zs[r][h0 + hh] = di * acc;
    }
    __syncthreads();
    U_PART(u1);
    BAR(1);
    LOAD_US(u1);

    // ---- layer 2 ----
#pragma unroll
    for (int hh = 0; hh < 4; ++hh) {
        int h = h0 + hh;
        float acc = 0.f;
#pragma unroll
        for (int t = 0; t < TT; ++t) acc += xns[t][r] * us[t][h];
        xs[r][h] = fmaxf(di * (acc + zs[r][h]) + b1s[h], 0.f);
    }
#pragma unroll
    for (int hh = 0; hh < 4; ++hh) {
        float acc = 0.f;
#pragma unroll
        for (int e = 0; e < 32; ++e) acc += xs[r][e] * W2s[e][h0 + hh];
        zs[r][h0 + hh] = di * acc;
    }
    __syncthreads();
    U_PART(u2);
    BAR(2);
    LOAD_US(u2);

    // ---- final B -> out ----
    float o[4];
#pragma unroll
    for (int hh = 0; hh < 4; ++hh) {
        int h = h0 + hh;
        float acc = 0.f;
#pragma unroll
        for (int t = 0; t < TT; ++t) acc += xns[t][r] * us[t][h];
        o[hh] = fmaxf(di * (acc + zs[r][h]) + b2s[h], 0.f);
    }
    float* orow = out + ((size_t)b * NN + j0 + r) * HH + h0;
    ((float4*)orow)[0] = make_float4(o[0], o[1], o[2], o[3]);

#undef U_PART
#undef BAR
#undef LOAD_US
}

extern "C" void kernel_launch(void* const* d_in, const int* in_sizes, int n_in,
                              void* d_out, int out_size, void* d_ws, size_t ws_size,
                              hipStream_t stream) {
    const float* Flow = (const float*)d_in[0];
    const float* Edge = (const float*)d_in[1];
    const float* W0 = (const float*)d_in[2];
    const float* b0 = (const float*)d_in[3];
    const float* W1 = (const float*)d_in[4];
    const float* b1 = (const float*)d_in[5];
    const float* W2 = (const float*)d_in[6];
    const float* b2 = (const float*)d_in[7];
    float* out = (float*)d_out;

    float* ws = (float*)d_ws;
    float* rn = ws;                               // B*T
    float* s  = rn + BB * TT;                     // B*T
    float* u  = s + BB * TT;                      // 3*B*T*H
    unsigned* ctr = (unsigned*)(u + 3 * BB * UPB); // 3*B*CTRS words

    k_norm<<<dim3(BB * TT), 256, 0, stream>>>(Flow, rn, s, u);
    k_mega<<<dim3(BB * NBLK), 256, 0, stream>>>(Flow, Edge, W0, W1, W2,
                                                b0, b1, b2, rn, s, u, ctr, out);
}

// Round 10
// 62.053 us; speedup vs baseline: 1.7814x; 1.7814x over previous
//
#include <hip/hip_runtime.h>

#define BB 8
#define TT 24
#define NN 4096   // C*C
#define HH 32
#define JT 128    // j-tile width
#define NJ 32     // j-blocks per batch
#define UPB (TT*HH)  // 768
#define CTRS 16

#define SM_OFF 192
#define U_OFF 384
#define U_WORDS (3*BB*UPB)     // 18432
#define CTR_WORDS (4*BB*CTRS)  // 512
#define ZERO_WORDS (U_OFF + U_WORDS + CTR_WORDS)

// ---------------- K0: zero sq/sm/u/ctr ----------------
__global__ __launch_bounds__(256) void k_zero(float* __restrict__ ws) {
    int i = blockIdx.x * 256 + threadIdx.x;
    if (i < ZERO_WORDS) ws[i] = 0.f;
}

// ---------------- K1: phase-specialized dataflow pipeline ----------------
// phase = blk>>8 (0..3); each phase-group recomputes the j-local chain and
// consumes u_{l} via R7-validated relaxed memory-side flags (fan-in 32).
__global__ __launch_bounds__(256, 4) void k_mega(const float* __restrict__ Flow,
                                                 const float* __restrict__ Edge,
                                                 const float* __restrict__ W0,
                                                 const float* __restrict__ W1,
                                                 const float* __restrict__ W2,
                                                 const float* __restrict__ b0,
                                                 const float* __restrict__ b1,
                                                 const float* __restrict__ b2,
                                                 float* __restrict__ ws,
                                                 float* __restrict__ out) {
    float* sq = ws;
    float* sm = ws + SM_OFF;
    float* u  = ws + U_OFF;
    unsigned* ctr = (unsigned*)(ws + U_OFF + U_WORDS);

    const int blk = blockIdx.x;
    const int phase = blk >> 8;
    const int b = (blk >> 5) & 7;
    const int j0 = (blk & 31) * JT;
    const int tid = threadIdx.x;

    __shared__ float xns[TT][JT];     // 12 KB
    __shared__ float zs[JT][33];      // 16.5 KB
    __shared__ float us[TT][HH];      // 3 KB
    __shared__ float Ws[32][32];      // 4 KB
    __shared__ float rnS[TT], sS[TT];
    __shared__ float biasS[3][32];

    // Edge half-row -> regs (row j0 + tid/2, half tid&1) — coalesced
    float er[16];
    {
        const float4* ep = (const float4*)(Edge + ((size_t)b * NN + j0 + (tid >> 1)) * HH) + (tid & 1) * 4;
#pragma unroll
        for (int q = 0; q < 4; ++q) {
            float4 v = ep[q];
            er[q*4+0] = v.x; er[q*4+1] = v.y; er[q*4+2] = v.z; er[q*4+3] = v.w;
        }
    }
    // Flow tile raw -> xns
    {
        const float4* fp = (const float4*)(Flow + (size_t)b * TT * NN) + (j0 >> 2);
        for (int i = tid; i < TT * (JT / 4); i += 256) {
            int t = i >> 5, c = i & 31;
            float4 v = fp[(size_t)t * (NN / 4) + c];
            xns[t][c*4+0] = v.x; xns[t][c*4+1] = v.y;
            xns[t][c*4+2] = v.z; xns[t][c*4+3] = v.w;
        }
    }
    if (tid < 32) { biasS[0][tid] = b0[tid]; biasS[1][tid] = b1[tid]; biasS[2][tid] = b2[tid]; }
    for (int i = tid; i < 1024; i += 256) Ws[i >> 5][i & 31] = W0[i];
    __syncthreads();

#define INC_FLAG(f)                                                                 \
    { __syncthreads();                                                              \
      if (tid == 0)                                                                 \
          __hip_atomic_fetch_add(&ctr[((f)*BB+b)*CTRS], 1u, __ATOMIC_RELAXED,       \
                                 __HIP_MEMORY_SCOPE_AGENT); }

#define WAIT_FLAG(f)                                                                \
    { __syncthreads();                                                              \
      if (tid == 0) {                                                               \
          unsigned* c = &ctr[((f)*BB+b)*CTRS];                                      \
          int lim = 1 << 20;                                                        \
          while (__hip_atomic_load(c, __ATOMIC_RELAXED, __HIP_MEMORY_SCOPE_AGENT)   \
                     < (unsigned)NJ && --lim)                                       \
              __builtin_amdgcn_s_sleep(2);                                          \
      }                                                                             \
      __syncthreads(); }

#define LOAD_US(l)                                                                  \
    { _Pragma("unroll")                                                             \
      for (int k = 0; k < 3; ++k) {                                                 \
          int p = tid + k * 256;                                                    \
          us[p >> 5][p & 31] = __hip_atomic_load(&u[((l)*BB+b)*UPB + p],            \
                                                 __ATOMIC_RELAXED,                  \
                                                 __HIP_MEMORY_SCOPE_AGENT);         \
      }                                                                             \
      __syncthreads(); }

#define U_PART(l)                                                                   \
    { __syncthreads();                                                              \
      _Pragma("unroll")                                                             \
      for (int k = 0; k < 3; ++k) {                                                 \
          int p = tid + k * 256;                                                    \
          int t = p >> 5, h = p & 31;                                               \
          float acc = 0.f;                                                          \
          _Pragma("unroll 16")                                                      \
          for (int rr = 0; rr < JT; ++rr) acc += xns[t][rr] * zs[rr][h];            \
          atomicAdd(&u[((l)*BB+b)*UPB + p], acc);                                   \
      } }

    // ---- P1 only: norm partials for this tile (raw xns) ----
    if (phase == 0) {
        if (tid < 192) {
            int t = tid >> 3, c0 = (tid & 7) * 16;
            float psq = 0.f, psm = 0.f;
#pragma unroll
            for (int jj = 0; jj < 16; ++jj) { float v = xns[t][c0 + jj]; psq += v * v; psm += v; }
#pragma unroll
            for (int off = 4; off > 0; off >>= 1) {
                psq += __shfl_down(psq, off);
                psm += __shfl_down(psm, off);
            }
            if ((tid & 7) == 0) { atomicAdd(&sq[b*TT+t], psq); atomicAdd(&sm[b*TT+t], psm); }
        }
        INC_FLAG(0);
    }
    WAIT_FLAG(0);
    if (tid < TT) {
        float q = __hip_atomic_load(&sq[b*TT+tid], __ATOMIC_RELAXED, __HIP_MEMORY_SCOPE_AGENT);
        float m = __hip_atomic_load(&sm[b*TT+tid], __ATOMIC_RELAXED, __HIP_MEMORY_SCOPE_AGENT);
        float rr = 1.0f / fmaxf(sqrtf(q), 1e-12f);
        rnS[tid] = rr; sS[tid] = m * rr;
    }
    __syncthreads();
    for (int i = tid; i < TT * JT; i += 256) xns[i >> 7][i & 127] *= rnS[i >> 7];
    __syncthreads();

    const int r = tid >> 1;
    const int h0 = (tid & 1) * 16;
    float deg = 1.0f;
#pragma unroll
    for (int t = 0; t < TT; ++t) deg += xns[t][r] * sS[t];
    const float di = (deg > 0.f) ? rsqrtf(deg) : 0.f;

    // z0 = di*(Edge_row @ W0); row assembled from half-rows via shfl_xor(1)
    float xrow[32], z[16];
#pragma unroll
    for (int k = 0; k < 16; ++k) {
        float a = er[k];
        float o = __shfl_xor(a, 1);
        xrow[k]      = (tid & 1) ? o : a;
        xrow[16 + k] = (tid & 1) ? a : o;
    }
#pragma unroll
    for (int hh = 0; hh < 16; ++hh) {
        float acc = 0.f;
#pragma unroll
        for (int e = 0; e < 32; ++e) acc += xrow[e] * Ws[e][h0 + hh];
        z[hh] = di * acc;
    }

#define STORE_ZS() { _Pragma("unroll") for (int hh = 0; hh < 16; ++hh) zs[r][h0 + hh] = z[hh]; }

#define B_PHASE(LIDX, xrel)                                                         \
    { _Pragma("unroll")                                                             \
      for (int hh = 0; hh < 16; ++hh) {                                             \
          int h = h0 + hh; float acc = 0.f;                                         \
          _Pragma("unroll")                                                         \
          for (int t = 0; t < TT; ++t) acc += xns[t][r] * us[t][h];                 \
          (xrel)[hh] = fmaxf(di * (acc + z[hh]) + biasS[LIDX][h], 0.f);             \
      } }

#define A_PHASE(xrel)                                                               \
    { _Pragma("unroll")                                                             \
      for (int k = 0; k < 16; ++k) {                                                \
          float a = (xrel)[k]; float o = __shfl_xor(a, 1);                          \
          xrow[k]      = (tid & 1) ? o : a;                                         \
          xrow[16 + k] = (tid & 1) ? a : o;                                         \
      }                                                                             \
      _Pragma("unroll")                                                             \
      for (int hh = 0; hh < 16; ++hh) {                                             \
          float acc = 0.f;                                                          \
          _Pragma("unroll")                                                         \
          for (int e = 0; e < 32; ++e) acc += xrow[e] * Ws[e][h0 + hh];             \
          z[hh] = di * acc;                                                         \
      } }

    if (phase == 0) {
        STORE_ZS();
        U_PART(0);
        INC_FLAG(1);
        return;
    }
    __syncthreads();                      // done reading Ws=W0
    for (int i = tid; i < 1024; i += 256) Ws[i >> 5][i & 31] = W1[i];
    WAIT_FLAG(1);
    LOAD_US(0);
    float xrel[16];
    B_PHASE(0, xrel);
    A_PHASE(xrel);                        // z = z1 (W1)
    if (phase == 1) {
        STORE_ZS();
        U_PART(1);
        INC_FLAG(2);
        return;
    }
    __syncthreads();
    for (int i = tid; i < 1024; i += 256) Ws[i >> 5][i & 31] = W2[i];
    WAIT_FLAG(2);
    LOAD_US(1);
    B_PHASE(1, xrel);
    A_PHASE(xrel);                        // z = z2 (W2)
    if (phase == 2) {
        STORE_ZS();
        U_PART(2);
        INC_FLAG(3);
        return;
    }
    WAIT_FLAG(3);
    LOAD_US(2);
    float o4[16];
#pragma unroll
    for (int hh = 0; hh < 16; ++hh) {
        int h = h0 + hh;
        float acc = 0.f;
#pragma unroll
        for (int t = 0; t < TT; ++t) acc += xns[t][r] * us[t][h];
        o4[hh] = fmaxf(di * (acc + z[hh]) + biasS[2][h], 0.f);
    }
    float4* op = (float4*)(out + ((size_t)b * NN + j0 + r) * HH + h0);
#pragma unroll
    for (int q = 0; q < 4; ++q)
        op[q] = make_float4(o4[4*q], o4[4*q+1], o4[4*q+2], o4[4*q+3]);

#undef INC_FLAG
#undef WAIT_FLAG
#undef LOAD_US
#undef U_PART
#undef STORE_ZS
#undef B_PHASE
#undef A_PHASE
}

extern "C" void kernel_launch(void* const* d_in, const int* in_sizes, int n_in,
                              void* d_out, int out_size, void* d_ws, size_t ws_size,
                              hipStream_t stream) {
    const float* Flow = (const float*)d_in[0];
    const float* Edge = (const float*)d_in[1];
    const float* W0 = (const float*)d_in[2];
    const float* b0 = (const float*)d_in[3];
    const float* W1 = (const float*)d_in[4];
    const float* b1 = (const float*)d_in[5];
    const float* W2 = (const float*)d_in[6];
    const float* b2 = (const float*)d_in[7];
    float* out = (float*)d_out;
    float* ws = (float*)d_ws;

    k_zero<<<dim3((ZERO_WORDS + 255) / 256), 256, 0, stream>>>(ws);
    k_mega<<<dim3(4 * BB * NJ), 256, 0, stream>>>(Flow, Edge, W0, W1, W2,
                                                  b0, b1, b2, ws, out);
}

// Round 11
// 43.654 us; speedup vs baseline: 2.5322x; 1.4215x over previous
//
#include <hip/hip_runtime.h>

#define BB 8
#define TT 24
#define NN 4096   // C*C
#define HH 32
#define JT 64     // j-tile width
#define UPB (TT*HH) // 768
#define CTRS 16   // counter stride (words)

// ---------------- K1: norm (192 blocks) + z0raw = Edge@W0 (512 blocks) ----------------
// Also zeroes u accumulators (u0,u1,u2) and the k_BAfin barrier counters.
__global__ __launch_bounds__(256) void k_phase1(const float* __restrict__ Flow,
                                                const float* __restrict__ Edge,
                                                const float* __restrict__ W0,
                                                float* __restrict__ rn,
                                                float* __restrict__ s,
                                                float* __restrict__ uz /* u + ctr zero region */,
                                                float* __restrict__ z0raw) {
    const int blk = blockIdx.x;
    const int tid = threadIdx.x;

    if (blk < BB * TT) {
        const float4* x = (const float4*)(Flow + (size_t)blk * NN);
        float sq = 0.f, sm = 0.f;
#pragma unroll
        for (int i = 0; i < 4; ++i) {
            float4 v = x[tid + i * 256];
            sq += v.x * v.x + v.y * v.y + v.z * v.z + v.w * v.w;
            sm += v.x + v.y + v.z + v.w;
        }
#pragma unroll
        for (int off = 32; off > 0; off >>= 1) {
            sq += __shfl_down(sq, off);
            sm += __shfl_down(sm, off);
        }
        __shared__ float rss[4], rsm[4];
        int wave = tid >> 6, lane = tid & 63;
        if (lane == 0) { rss[wave] = sq; rsm[wave] = sm; }
        __syncthreads();
        if (tid == 0) {
            float tss = rss[0] + rss[1] + rss[2] + rss[3];
            float tsm = rsm[0] + rsm[1] + rsm[2] + rsm[3];
            float r = 1.0f / fmaxf(sqrtf(tss), 1e-12f);
            rn[blk] = r;
            s[blk] = tsm * r;
        }
        // zero u (18432 floats) + ctr (BB*CTRS = 128 words) = 18560
        int gid = blk * 256 + tid;
        if (gid < 3 * BB * TT * HH + BB * CTRS) uz[gid] = 0.f;
    } else {
        const int g = blk - BB * TT;
        const int b = g >> 6;
        const int j0 = (g & 63) * JT;

        __shared__ float xs[JT][33];
        __shared__ float Ws[32][32];
        for (int i = tid; i < 1024; i += 256) Ws[i >> 5][i & 31] = W0[i];
        {
            const float4* eb = (const float4*)(Edge + ((size_t)b * NN + j0) * HH);
#pragma unroll
            for (int k = 0; k < 2; ++k) {
                int i = tid + k * 256;
                float4 v = eb[i];
                int r0 = i >> 3, c0 = (i & 7) * 4;
                xs[r0][c0] = v.x; xs[r0][c0 + 1] = v.y; xs[r0][c0 + 2] = v.z; xs[r0][c0 + 3] = v.w;
            }
        }
        __syncthreads();
        const int r = tid >> 2;
        const int h0 = (tid & 3) * 8;
        float zr[8];
#pragma unroll
        for (int hh = 0; hh < 8; ++hh) {
            float acc = 0.f;
#pragma unroll
            for (int e = 0; e < 32; ++e) acc += xs[r][e] * Ws[e][h0 + hh];
            zr[hh] = acc;
        }
        float* zb = z0raw + ((size_t)b * NN + j0 + r) * HH + h0;
        ((float4*)zb)[0] = make_float4(zr[0], zr[1], zr[2], zr[3]);
        ((float4*)zb)[1] = make_float4(zr[4], zr[5], zr[6], zr[7]);
    }
}

// ---------------- K2: dinv + u0 partials (no z write) ----------------
__global__ __launch_bounds__(256) void k_dinvU0(const float* __restrict__ Flow,
                                                const float* __restrict__ rn,
                                                const float* __restrict__ s,
                                                const float* __restrict__ z0raw,
                                                float* __restrict__ dinv,
                                                float* __restrict__ u0) {
    const int blk = blockIdx.x;
    const int b = blk >> 6;
    const int j0 = (blk & 63) * JT;
    const int tid = threadIdx.x;

    __shared__ float xns[TT][JT];
    __shared__ float zs[JT][33];
    __shared__ float sS[TT];

    if (tid < TT) sS[tid] = s[b * TT + tid];
    {
        const float4* zt = (const float4*)(z0raw + ((size_t)b * NN + j0) * HH);
#pragma unroll
        for (int k = 0; k < 2; ++k) {
            int i = tid + k * 256;
            float4 v = zt[i];
            int r0 = i >> 3, c0 = (i & 7) * 4;
            zs[r0][c0] = v.x; zs[r0][c0 + 1] = v.y; zs[r0][c0 + 2] = v.z; zs[r0][c0 + 3] = v.w;
        }
    }
    {
        const float* flb = Flow + (size_t)b * TT * NN + j0;
        for (int i = tid; i < TT * (JT / 4); i += 256) {
            int t = i >> 4, c0 = (i & 15) * 4;
            float4 v = ((const float4*)(flb + t * NN))[i & 15];
            float rt = rn[b * TT + t];
            xns[t][c0] = v.x * rt; xns[t][c0 + 1] = v.y * rt;
            xns[t][c0 + 2] = v.z * rt; xns[t][c0 + 3] = v.w * rt;
        }
    }
    __syncthreads();

    const int r = tid >> 2;
    const int h0 = (tid & 3) * 8;
    float deg = 1.0f;
#pragma unroll
    for (int t = 0; t < TT; ++t) deg += xns[t][r] * sS[t];
    const float di = (deg > 0.f) ? rsqrtf(deg) : 0.f;
    if ((tid & 3) == 0) dinv[b * NN + j0 + r] = di;
#pragma unroll
    for (int hh = 0; hh < 8; ++hh) zs[r][h0 + hh] *= di;
    __syncthreads();

#pragma unroll
    for (int k = 0; k < 3; ++k) {
        int p = tid + k * 256;
        int t = p >> 5, h = p & 31;
        float acc = 0.f;
#pragma unroll 8
        for (int rr = 0; rr < JT; ++rr) acc += xns[t][rr] * zs[rr][h];
        atomicAdd(&u0[(b * TT + t) * HH + h], acc);
    }
}

// ---------------- K3: fused B(0)+A(1), raw-z in/out ----------------
__global__ __launch_bounds__(256) void k_BA(const float* __restrict__ zraw_in,
                                            const float* __restrict__ Flow,
                                            const float* __restrict__ rn,
                                            const float* __restrict__ u_in,
                                            const float* __restrict__ dinv,
                                            const float* __restrict__ bias,
                                            const float* __restrict__ W,
                                            float* __restrict__ zraw_out,
                                            float* __restrict__ u_out) {
    const int blk = blockIdx.x;
    const int b = blk >> 6;
    const int j0 = (blk & 63) * JT;
    const int tid = threadIdx.x;

    __shared__ float us[TT][32];
    __shared__ float xns[TT][JT];
    __shared__ float Ws[32][32];
    __shared__ float xs[JT][33];
    __shared__ float zs[JT][33];
    __shared__ float bs[32];

    if (tid < 32) bs[tid] = bias[tid];
    for (int i = tid; i < 1024; i += 256) Ws[i >> 5][i & 31] = W[i];
    if (tid < UPB / 4) {
        float4 v = ((const float4*)(u_in + b * UPB))[tid];
        int t = tid >> 3, c0 = (tid & 7) * 4;
        us[t][c0] = v.x; us[t][c0 + 1] = v.y; us[t][c0 + 2] = v.z; us[t][c0 + 3] = v.w;
    }
    {
        const float4* zt = (const float4*)(zraw_in + ((size_t)b * NN + j0) * HH);
#pragma unroll
        for (int k = 0; k < 2; ++k) {
            int i = tid + k * 256;
            float4 v = zt[i];
            int r0 = i >> 3, c0 = (i & 7) * 4;
            zs[r0][c0] = v.x; zs[r0][c0 + 1] = v.y; zs[r0][c0 + 2] = v.z; zs[r0][c0 + 3] = v.w;
        }
    }
    {
        const float* flb = Flow + (size_t)b * TT * NN + j0;
        for (int i = tid; i < TT * (JT / 4); i += 256) {
            int t = i >> 4, c0 = (i & 15) * 4;
            float4 v = ((const float4*)(flb + t * NN))[i & 15];
            float rt = rn[b * TT + t];
            xns[t][c0] = v.x * rt; xns[t][c0 + 1] = v.y * rt;
            xns[t][c0 + 2] = v.z * rt; xns[t][c0 + 3] = v.w * rt;
        }
    }
    const int r = tid >> 2;
    const int h0 = (tid & 3) * 8;
    const float di = dinv[b * NN + j0 + r];
    __syncthreads();

    float zreg[8];
#pragma unroll
    for (int hh = 0; hh < 8; ++hh) zreg[hh] = di * zs[r][h0 + hh];
#pragma unroll
    for (int hh = 0; hh < 8; ++hh) {
        int h = h0 + hh;
        float acc = 0.f;
#pragma unroll
        for (int t = 0; t < TT; ++t) acc += xns[t][r] * us[t][h];
        xs[r][h] = fmaxf(di * (acc + zreg[hh]) + bs[h], 0.f);
    }
    // A-phase: threads 4r..4r+3 (same wave64) wrote xs[r][0..31]; same-wave LDS
    // program-order visibility (validated R1..R9)
    float zr[8];
#pragma unroll
    for (int hh = 0; hh < 8; ++hh) {
        float acc = 0.f;
#pragma unroll
        for (int e = 0; e < 32; ++e) acc += xs[r][e] * Ws[e][h0 + hh];
        zr[hh] = acc;                    // raw
        zs[r][h0 + hh] = di * zr[hh];    // scaled, for u partial
    }
    float* zb = zraw_out + ((size_t)b * NN + j0 + r) * HH + h0;
    ((float4*)zb)[0] = make_float4(zr[0], zr[1], zr[2], zr[3]);
    ((float4*)zb)[1] = make_float4(zr[4], zr[5], zr[6], zr[7]);
    __syncthreads();

#pragma unroll
    for (int k = 0; k < 3; ++k) {
        int p = tid + k * 256;
        int t = p >> 5, h = p & 31;
        float acc = 0.f;
#pragma unroll 8
        for (int rr = 0; rr < JT; ++rr) acc += xns[t][rr] * zs[rr][h];
        atomicAdd(&u_out[(b * TT + t) * HH + h], acc);
    }
}

// ---------------- K4: fused B(1)+A(2) + [in-kernel u2 barrier] + final B -> out ----------------
// z2 never touches global. Barrier = R7-validated relaxed memory-side counter.
__global__ __launch_bounds__(256, 2) void k_BAfin(const float* __restrict__ zraw_in,
                                                  const float* __restrict__ Flow,
                                                  const float* __restrict__ rn,
                                                  const float* __restrict__ u_in,
                                                  const float* __restrict__ dinv,
                                                  const float* __restrict__ bias1,
                                                  const float* __restrict__ W2,
                                                  const float* __restrict__ bias2,
                                                  float* __restrict__ u2,
                                                  unsigned* __restrict__ ctr,
                                                  float* __restrict__ out) {
    const int blk = blockIdx.x;
    const int b = blk >> 6;
    const int j0 = (blk & 63) * JT;
    const int tid = threadIdx.x;

    __shared__ float us[TT][32];
    __shared__ float xns[TT][JT];
    __shared__ float Ws[32][32];
    __shared__ float xs[JT][33];
    __shared__ float zs[JT][33];
    __shared__ float b1s[32], b2s[32];

    if (tid < 32) { b1s[tid] = bias1[tid]; b2s[tid] = bias2[tid]; }
    for (int i = tid; i < 1024; i += 256) Ws[i >> 5][i & 31] = W2[i];
    if (tid < UPB / 4) {
        float4 v = ((const float4*)(u_in + b * UPB))[tid];
        int t = tid >> 3, c0 = (tid & 7) * 4;
        us[t][c0] = v.x; us[t][c0 + 1] = v.y; us[t][c0 + 2] = v.z; us[t][c0 + 3] = v.w;
    }
    {
        const float4* zt = (const float4*)(zraw_in + ((size_t)b * NN + j0) * HH);
#pragma unroll
        for (int k = 0; k < 2; ++k) {
            int i = tid + k * 256;
            float4 v = zt[i];
            int r0 = i >> 3, c0 = (i & 7) * 4;
            zs[r0][c0] = v.x; zs[r0][c0 + 1] = v.y; zs[r0][c0 + 2] = v.z; zs[r0][c0 + 3] = v.w;
        }
    }
    {
        const float* flb = Flow + (size_t)b * TT * NN + j0;
        for (int i = tid; i < TT * (JT / 4); i += 256) {
            int t = i >> 4, c0 = (i & 15) * 4;
            float4 v = ((const float4*)(flb + t * NN))[i & 15];
            float rt = rn[b * TT + t];
            xns[t][c0] = v.x * rt; xns[t][c0 + 1] = v.y * rt;
            xns[t][c0 + 2] = v.z * rt; xns[t][c0 + 3] = v.w * rt;
        }
    }
    const int r = tid >> 2;
    const int h0 = (tid & 3) * 8;
    const float di = dinv[b * NN + j0 + r];
    __syncthreads();

    // B(1): x2 rows
    float zreg[8];
#pragma unroll
    for (int hh = 0; hh < 8; ++hh) zreg[hh] = di * zs[r][h0 + hh];
#pragma unroll
    for (int hh = 0; hh < 8; ++hh) {
        int h = h0 + hh;
        float acc = 0.f;
#pragma unroll
        for (int t = 0; t < TT; ++t) acc += xns[t][r] * us[t][h];
        xs[r][h] = fmaxf(di * (acc + zreg[hh]) + b1s[h], 0.f);
    }
    // A(2): z2 scaled -> zs only (no global write)
#pragma unroll
    for (int hh = 0; hh < 8; ++hh) {
        float acc = 0.f;
#pragma unroll
        for (int e = 0; e < 32; ++e) acc += xs[r][e] * Ws[e][h0 + hh];
        zs[r][h0 + hh] = di * acc;
    }
    __syncthreads();

    // u2 partials (memory-side atomics)
#pragma unroll
    for (int k = 0; k < 3; ++k) {
        int p = tid + k * 256;
        int t = p >> 5, h = p & 31;
        float acc = 0.f;
#pragma unroll 8
        for (int rr = 0; rr < JT; ++rr) acc += xns[t][rr] * zs[rr][h];
        atomicAdd(&u2[b * UPB + t * HH + h], acc);
    }

    // relaxed per-batch barrier (fan-in 64; all 512 blocks resident at >=2/CU)
    __syncthreads();   // compiler drains vmcnt before s_barrier
    if (tid == 0) {
        unsigned* c = ctr + b * CTRS;
        __hip_atomic_fetch_add(c, 1u, __ATOMIC_RELAXED, __HIP_MEMORY_SCOPE_AGENT);
        int lim = 1 << 22;
        while (__hip_atomic_load(c, __ATOMIC_RELAXED, __HIP_MEMORY_SCOPE_AGENT) < 64u && --lim)
            __builtin_amdgcn_s_sleep(1);
    }
    __syncthreads();

    // consume u2 (uncached relaxed atomic loads)
#pragma unroll
    for (int k = 0; k < 3; ++k) {
        int p = tid + k * 256;
        us[p >> 5][p & 31] = __hip_atomic_load(&u2[b * UPB + p], __ATOMIC_RELAXED,
                                               __HIP_MEMORY_SCOPE_AGENT);
    }
    __syncthreads();

    // final B -> out (zs still holds di*z2)
    float o[8];
#pragma unroll
    for (int hh = 0; hh < 8; ++hh) {
        int h = h0 + hh;
        float acc = 0.f;
#pragma unroll
        for (int t = 0; t < TT; ++t) acc += xns[t][r] * us[t][h];
        o[hh] = fmaxf(di * (acc + zs[r][h]) + b2s[h], 0.f);
    }
    float* orow = out + ((size_t)b * NN + j0 + r) * HH + h0;
    ((float4*)orow)[0] = make_float4(o[0], o[1], o[2], o[3]);
    ((float4*)orow)[1] = make_float4(o[4], o[5], o[6], o[7]);
}

extern "C" void kernel_launch(void* const* d_in, const int* in_sizes, int n_in,
                              void* d_out, int out_size, void* d_ws, size_t ws_size,
                              hipStream_t stream) {
    const float* Flow = (const float*)d_in[0];
    const float* Edge = (const float*)d_in[1];
    const float* W0 = (const float*)d_in[2];
    const float* b0 = (const float*)d_in[3];
    const float* W1 = (const float*)d_in[4];
    const float* b1 = (const float*)d_in[5];
    const float* W2 = (const float*)d_in[6];
    const float* b2 = (const float*)d_in[7];
    float* out = (float*)d_out;

    float* ws = (float*)d_ws;
    float* rn    = ws;                                  // B*T
    float* s     = rn + BB * TT;                        // B*T
    float* dinv  = s + BB * TT;                         // B*N
    float* zA    = dinv + (size_t)BB * NN;              // B*N*H (raw)
    float* zB    = zA + (size_t)BB * NN * HH;           // B*N*H (raw)
    float* u     = zB + (size_t)BB * NN * HH;           // 3*B*T*H
    unsigned* ctr = (unsigned*)(u + 3 * BB * UPB);      // B*CTRS words
    float* u0 = u, *u1 = u + BB * UPB, *u2 = u + 2 * BB * UPB;

    k_phase1<<<dim3(BB * TT + 512), 256, 0, stream>>>(Flow, Edge, W0, rn, s, u, zA);
    k_dinvU0<<<dim3(512), 256, 0, stream>>>(Flow, rn, s, zA, dinv, u0);
    k_BA<<<dim3(512), 256, 0, stream>>>(zA, Flow, rn, u0, dinv, b0, W1, zB, u1);
    k_BAfin<<<dim3(512), 256, 0, stream>>>(zB, Flow, rn, u1, dinv, b1, W2, b2,
                                           u2, ctr, out);
}

// Round 12
// 41.686 us; speedup vs baseline: 2.6518x; 1.0472x over previous
//
#include <hip/hip_runtime.h>

#define BB 8
#define TT 24
#define NN 4096   // C*C
#define HH 32
#define JT 64     // j-tile width
#define UPB (TT*HH) // 768
#define CTRS 16   // counter stride (words)
#define NT 512    // threads per block

// ---------------- K1: norm (192 blocks) + z0raw = Edge@W0 (512 blocks) ----------------
__global__ __launch_bounds__(NT) void k_phase1(const float* __restrict__ Flow,
                                               const float* __restrict__ Edge,
                                               const float* __restrict__ W0,
                                               float* __restrict__ rn,
                                               float* __restrict__ s,
                                               float* __restrict__ uz,
                                               float* __restrict__ z0raw) {
    const int blk = blockIdx.x;
    const int tid = threadIdx.x;

    if (blk < BB * TT) {
        const float4* x = (const float4*)(Flow + (size_t)blk * NN);
        float sq = 0.f, sm = 0.f;
#pragma unroll
        for (int i = 0; i < 2; ++i) {
            float4 v = x[tid + i * NT];
            sq += v.x * v.x + v.y * v.y + v.z * v.z + v.w * v.w;
            sm += v.x + v.y + v.z + v.w;
        }
#pragma unroll
        for (int off = 32; off > 0; off >>= 1) {
            sq += __shfl_down(sq, off);
            sm += __shfl_down(sm, off);
        }
        __shared__ float rss[8], rsm[8];
        int wave = tid >> 6, lane = tid & 63;
        if (lane == 0) { rss[wave] = sq; rsm[wave] = sm; }
        __syncthreads();
        if (tid == 0) {
            float tss = 0.f, tsm = 0.f;
#pragma unroll
            for (int w = 0; w < 8; ++w) { tss += rss[w]; tsm += rsm[w]; }
            float r = 1.0f / fmaxf(sqrtf(tss), 1e-12f);
            rn[blk] = r;
            s[blk] = tsm * r;
        }
        // zero u (18432 floats) + ctr (128 words)
        int gid = blk * NT + tid;
        if (gid < 3 * BB * TT * HH + BB * CTRS) uz[gid] = 0.f;
    } else {
        const int g = blk - BB * TT;
        const int b = g >> 6;
        const int j0 = (g & 63) * JT;

        __shared__ float xs[JT][33];
        __shared__ float Ws[32][32];
        for (int i = tid; i < 1024; i += NT) Ws[i >> 5][i & 31] = W0[i];
        {
            float4 v = ((const float4*)(Edge + ((size_t)b * NN + j0) * HH))[tid];
            int r0 = tid >> 3, c0 = (tid & 7) * 4;
            xs[r0][c0] = v.x; xs[r0][c0 + 1] = v.y; xs[r0][c0 + 2] = v.z; xs[r0][c0 + 3] = v.w;
        }
        __syncthreads();
        const int r = tid >> 3;
        const int h0 = (tid & 7) * 4;
        float zr[4];
#pragma unroll
        for (int hh = 0; hh < 4; ++hh) {
            float acc = 0.f;
#pragma unroll
            for (int e = 0; e < 32; ++e) acc += xs[r][e] * Ws[e][h0 + hh];
            zr[hh] = acc;
        }
        float* zb = z0raw + ((size_t)b * NN + j0 + r) * HH + h0;
        ((float4*)zb)[0] = make_float4(zr[0], zr[1], zr[2], zr[3]);
    }
}

// ---------------- K2: dinv + u0 partials ----------------
__global__ __launch_bounds__(NT) void k_dinvU0(const float* __restrict__ Flow,
                                               const float* __restrict__ rn,
                                               const float* __restrict__ s,
                                               const float* __restrict__ z0raw,
                                               float* __restrict__ dinv,
                                               float* __restrict__ u0) {
    const int blk = blockIdx.x;
    const int b = blk >> 6;
    const int j0 = (blk & 63) * JT;
    const int tid = threadIdx.x;

    __shared__ float xns[TT][JT];
    __shared__ float zs[JT][33];
    __shared__ float sS[TT];

    if (tid < TT) sS[tid] = s[b * TT + tid];
    {
        float4 v = ((const float4*)(z0raw + ((size_t)b * NN + j0) * HH))[tid];
        int r0 = tid >> 3, c0 = (tid & 7) * 4;
        zs[r0][c0] = v.x; zs[r0][c0 + 1] = v.y; zs[r0][c0 + 2] = v.z; zs[r0][c0 + 3] = v.w;
    }
    if (tid < TT * (JT / 4)) {
        int t = tid >> 4, c0 = (tid & 15) * 4;
        float4 v = ((const float4*)(Flow + (size_t)b * TT * NN + (size_t)t * NN + j0))[tid & 15];
        float rt = rn[b * TT + t];
        xns[t][c0] = v.x * rt; xns[t][c0 + 1] = v.y * rt;
        xns[t][c0 + 2] = v.z * rt; xns[t][c0 + 3] = v.w * rt;
    }
    __syncthreads();

    const int r = tid >> 3;
    const int h0 = (tid & 7) * 4;
    float deg = 1.0f;
#pragma unroll
    for (int t = 0; t < TT; ++t) deg += xns[t][r] * sS[t];
    const float di = (deg > 0.f) ? rsqrtf(deg) : 0.f;
    if ((tid & 7) == 0) dinv[b * NN + j0 + r] = di;
#pragma unroll
    for (int hh = 0; hh < 4; ++hh) zs[r][h0 + hh] *= di;
    __syncthreads();

#pragma unroll
    for (int k = 0; k < 2; ++k) {
        int p = tid + k * NT;
        if (p < UPB) {
            int t = p >> 5, h = p & 31;
            float acc = 0.f;
#pragma unroll 8
            for (int rr = 0; rr < JT; ++rr) acc += xns[t][rr] * zs[rr][h];
            atomicAdd(&u0[b * UPB + t * HH + h], acc);
        }
    }
}

// ---------------- K3: fused B(0)+A(1), raw-z in/out ----------------
__global__ __launch_bounds__(NT) void k_BA(const float* __restrict__ zraw_in,
                                           const float* __restrict__ Flow,
                                           const float* __restrict__ rn,
                                           const float* __restrict__ u_in,
                                           const float* __restrict__ dinv,
                                           const float* __restrict__ bias,
                                           const float* __restrict__ W,
                                           float* __restrict__ zraw_out,
                                           float* __restrict__ u_out) {
    const int blk = blockIdx.x;
    const int b = blk >> 6;
    const int j0 = (blk & 63) * JT;
    const int tid = threadIdx.x;

    __shared__ float us[TT][32];
    __shared__ float xns[TT][JT];
    __shared__ float Ws[32][32];
    __shared__ float xs[JT][33];
    __shared__ float zs[JT][33];
    __shared__ float bs[32];

    if (tid < 32) bs[tid] = bias[tid];
    for (int i = tid; i < 1024; i += NT) Ws[i >> 5][i & 31] = W[i];
    if (tid < UPB / 4) {
        float4 v = ((const float4*)(u_in + b * UPB))[tid];
        int t = tid >> 3, c0 = (tid & 7) * 4;
        us[t][c0] = v.x; us[t][c0 + 1] = v.y; us[t][c0 + 2] = v.z; us[t][c0 + 3] = v.w;
    }
    {
        float4 v = ((const float4*)(zraw_in + ((size_t)b * NN + j0) * HH))[tid];
        int r0 = tid >> 3, c0 = (tid & 7) * 4;
        zs[r0][c0] = v.x; zs[r0][c0 + 1] = v.y; zs[r0][c0 + 2] = v.z; zs[r0][c0 + 3] = v.w;
    }
    if (tid < TT * (JT / 4)) {
        int t = tid >> 4, c0 = (tid & 15) * 4;
        float4 v = ((const float4*)(Flow + (size_t)b * TT * NN + (size_t)t * NN + j0))[tid & 15];
        float rt = rn[b * TT + t];
        xns[t][c0] = v.x * rt; xns[t][c0 + 1] = v.y * rt;
        xns[t][c0 + 2] = v.z * rt; xns[t][c0 + 3] = v.w * rt;
    }
    const int r = tid >> 3;
    const int h0 = (tid & 7) * 4;
    const float di = dinv[b * NN + j0 + r];
    __syncthreads();

    float zreg[4];
#pragma unroll
    for (int hh = 0; hh < 4; ++hh) zreg[hh] = di * zs[r][h0 + hh];
#pragma unroll
    for (int hh = 0; hh < 4; ++hh) {
        int h = h0 + hh;
        float acc = 0.f;
#pragma unroll
        for (int t = 0; t < TT; ++t) acc += xns[t][r] * us[t][h];
        xs[r][h] = fmaxf(di * (acc + zreg[hh]) + bs[h], 0.f);
    }
    // A-phase: threads 8r..8r+7 (contiguous within one wave64) wrote xs[r][0..31];
    // same-wave program-order LDS visibility (validated R1..R10)
    float zr[4];
#pragma unroll
    for (int hh = 0; hh < 4; ++hh) {
        float acc = 0.f;
#pragma unroll
        for (int e = 0; e < 32; ++e) acc += xs[r][e] * Ws[e][h0 + hh];
        zr[hh] = acc;                    // raw
        zs[r][h0 + hh] = di * zr[hh];    // scaled, for u partial
    }
    float* zb = zraw_out + ((size_t)b * NN + j0 + r) * HH + h0;
    ((float4*)zb)[0] = make_float4(zr[0], zr[1], zr[2], zr[3]);
    __syncthreads();

#pragma unroll
    for (int k = 0; k < 2; ++k) {
        int p = tid + k * NT;
        if (p < UPB) {
            int t = p >> 5, h = p & 31;
            float acc = 0.f;
#pragma unroll 8
            for (int rr = 0; rr < JT; ++rr) acc += xns[t][rr] * zs[rr][h];
            atomicAdd(&u_out[b * UPB + t * HH + h], acc);
        }
    }
}

// ---------------- K4: fused B(1)+A(2) + in-kernel u2 barrier + final B -> out ----------------
__global__ __launch_bounds__(NT, 4) void k_BAfin(const float* __restrict__ zraw_in,
                                                 const float* __restrict__ Flow,
                                                 const float* __restrict__ rn,
                                                 const float* __restrict__ u_in,
                                                 const float* __restrict__ dinv,
                                                 const float* __restrict__ bias1,
                                                 const float* __restrict__ W2,
                                                 const float* __restrict__ bias2,
                                                 float* __restrict__ u2,
                                                 unsigned* __restrict__ ctr,
                                                 float* __restrict__ out) {
    const int blk = blockIdx.x;
    const int b = blk >> 6;
    const int j0 = (blk & 63) * JT;
    const int tid = threadIdx.x;

    __shared__ float us[TT][32];
    __shared__ float xns[TT][JT];
    __shared__ float Ws[32][32];
    __shared__ float xs[JT][33];
    __shared__ float zs[JT][33];
    __shared__ float b1s[32], b2s[32];

    if (tid < 32) { b1s[tid] = bias1[tid]; b2s[tid] = bias2[tid]; }
    for (int i = tid; i < 1024; i += NT) Ws[i >> 5][i & 31] = W2[i];
    if (tid < UPB / 4) {
        float4 v = ((const float4*)(u_in + b * UPB))[tid];
        int t = tid >> 3, c0 = (tid & 7) * 4;
        us[t][c0] = v.x; us[t][c0 + 1] = v.y; us[t][c0 + 2] = v.z; us[t][c0 + 3] = v.w;
    }
    {
        float4 v = ((const float4*)(zraw_in + ((size_t)b * NN + j0) * HH))[tid];
        int r0 = tid >> 3, c0 = (tid & 7) * 4;
        zs[r0][c0] = v.x; zs[r0][c0 + 1] = v.y; zs[r0][c0 + 2] = v.z; zs[r0][c0 + 3] = v.w;
    }
    if (tid < TT * (JT / 4)) {
        int t = tid >> 4, c0 = (tid & 15) * 4;
        float4 v = ((const float4*)(Flow + (size_t)b * TT * NN + (size_t)t * NN + j0))[tid & 15];
        float rt = rn[b * TT + t];
        xns[t][c0] = v.x * rt; xns[t][c0 + 1] = v.y * rt;
        xns[t][c0 + 2] = v.z * rt; xns[t][c0 + 3] = v.w * rt;
    }
    const int r = tid >> 3;
    const int h0 = (tid & 7) * 4;
    const float di = dinv[b * NN + j0 + r];
    __syncthreads();

    // B(1): x2 rows
    float zreg[4];
#pragma unroll
    for (int hh = 0; hh < 4; ++hh) zreg[hh] = di * zs[r][h0 + hh];
#pragma unroll
    for (int hh = 0; hh < 4; ++hh) {
        int h = h0 + hh;
        float acc = 0.f;
#pragma unroll
        for (int t = 0; t < TT; ++t) acc += xns[t][r] * us[t][h];
        xs[r][h] = fmaxf(di * (acc + zreg[hh]) + b1s[h], 0.f);
    }
    // A(2): z2 scaled -> zs only (no global write)
#pragma unroll
    for (int hh = 0; hh < 4; ++hh) {
        float acc = 0.f;
#pragma unroll
        for (int e = 0; e < 32; ++e) acc += xs[r][e] * Ws[e][h0 + hh];
        zs[r][h0 + hh] = di * acc;
    }
    __syncthreads();

    // u2 partials (memory-side atomics)
#pragma unroll
    for (int k = 0; k < 2; ++k) {
        int p = tid + k * NT;
        if (p < UPB) {
            int t = p >> 5, h = p & 31;
            float acc = 0.f;
#pragma unroll 8
            for (int rr = 0; rr < JT; ++rr) acc += xns[t][rr] * zs[rr][h];
            atomicAdd(&u2[b * UPB + t * HH + h], acc);
        }
    }

    // relaxed per-batch barrier (fan-in 64; all 512 blocks resident at 2/CU)
    __syncthreads();   // compiler drains vmcnt before s_barrier
    if (tid == 0) {
        unsigned* c = ctr + b * CTRS;
        __hip_atomic_fetch_add(c, 1u, __ATOMIC_RELAXED, __HIP_MEMORY_SCOPE_AGENT);
        int lim = 1 << 22;
        while (__hip_atomic_load(c, __ATOMIC_RELAXED, __HIP_MEMORY_SCOPE_AGENT) < 64u && --lim)
            __builtin_amdgcn_s_sleep(1);
    }
    __syncthreads();

    // consume u2 (uncached relaxed atomic loads)
#pragma unroll
    for (int k = 0; k < 2; ++k) {
        int p = tid + k * NT;
        if (p < UPB)
            us[p >> 5][p & 31] = __hip_atomic_load(&u2[b * UPB + p], __ATOMIC_RELAXED,
                                                   __HIP_MEMORY_SCOPE_AGENT);
    }
    __syncthreads();

    // final B -> out (zs still holds di*z2)
    float o[4];
#pragma unroll
    for (int hh = 0; hh < 4; ++hh) {
        int h = h0 + hh;
        float acc = 0.f;
#pragma unroll
        for (int t = 0; t < TT; ++t) acc += xns[t][r] * us[t][h];
        o[hh] = fmaxf(di * (acc + zs[r][h]) + b2s[h], 0.f);
    }
    float* orow = out + ((size_t)b * NN + j0 + r) * HH + h0;
    ((float4*)orow)[0] = make_float4(o[0], o[1], o[2], o[3]);
}

extern "C" void kernel_launch(void* const* d_in, const int* in_sizes, int n_in,
                              void* d_out, int out_size, void* d_ws, size_t ws_size,
                              hipStream_t stream) {
    const float* Flow = (const float*)d_in[0];
    const float* Edge = (const float*)d_in[1];
    const float* W0 = (const float*)d_in[2];
    const float* b0 = (const float*)d_in[3];
    const float* W1 = (const float*)d_in[4];
    const float* b1 = (const float*)d_in[5];
    const float* W2 = (const float*)d_in[6];
    const float* b2 = (const float*)d_in[7];
    float* out = (float*)d_out;

    float* ws = (float*)d_ws;
    float* rn    = ws;                                  // B*T
    float* s     = rn + BB * TT;                        // B*T
    float* dinv  = s + BB * TT;                         // B*N
    float* zA    = dinv + (size_t)BB * NN;              // B*N*H (raw)
    float* zB    = zA + (size_t)BB * NN * HH;           // B*N*H (raw)
    float* u     = zB + (size_t)BB * NN * HH;           // 3*B*T*H
    unsigned* ctr = (unsigned*)(u + 3 * BB * UPB);      // B*CTRS words
    float* u0 = u, *u1 = u + BB * UPB, *u2 = u + 2 * BB * UPB;

    k_phase1<<<dim3(BB * TT + 512), NT, 0, stream>>>(Flow, Edge, W0, rn, s, u, zA);
    k_dinvU0<<<dim3(512), NT, 0, stream>>>(Flow, rn, s, zA, dinv, u0);
    k_BA<<<dim3(512), NT, 0, stream>>>(zA, Flow, rn, u0, dinv, b0, W1, zB, u1);
    k_BAfin<<<dim3(512), NT, 0, stream>>>(zB, Flow, rn, u1, dinv, b1, W2, b2,
                                          u2, ctr, out);
}